// Round 5
// baseline (382.948 us; speedup 1.0000x reference)
//
#include <hip/hip_runtime.h>

// Simple_Cross2: x[16384,512] -> cross -> 2048 -> 2048 -> 1024 -> 512 -> 1
// bf16 MFMA GEMMs, fp32 accumulate, fused bias+relu.
// R2: BK=64 + XOR swizzle -> 0 bank conflicts.
// R3: 64x128 wave tile, block 128x256 -> MfmaUtil 50%, G2 119us.
// R4 FAILED (reverted): dbuf prefetch — __syncthreads drains vmcnt(0) incl.
//     the prefetch itself; structural, per m99/m131-141.
// R5: MFMA shape 16x16x32 -> 32x32x16 (µbench 2382 vs 2075 TF: +17% matrix
//     pipe, half the MFMA instructions). Same geometry, same swizzled LDS,
//     same staging; only fragment addressing + epilogue mapping change.
//     A[m=lane&31][k=(lane>>5)*8+j]; C/D col=lane&31,
//     row=(reg&3)+8*(reg>>2)+4*(lane>>5)  [m74/m101].

#define BK 64

typedef __bf16 bf16x8 __attribute__((ext_vector_type(8)));
typedef float  f32x4  __attribute__((ext_vector_type(4)));
typedef float  f32x16 __attribute__((ext_vector_type(16)));
typedef unsigned short u16x4 __attribute__((ext_vector_type(4)));

__device__ __forceinline__ unsigned short f2bf(float f) {
    unsigned int u = __builtin_bit_cast(unsigned int, f);
    u += 0x7fffu + ((u >> 16) & 1u);          // round-to-nearest-even
    return (unsigned short)(u >> 16);
}
__device__ __forceinline__ float bf2f(unsigned short h) {
    unsigned int u = ((unsigned int)h) << 16;
    return __builtin_bit_cast(float, u);
}

__device__ __forceinline__ void async16(const void* g, void* l) {
    __builtin_amdgcn_global_load_lds(
        (const __attribute__((address_space(1))) unsigned int*)g,
        (__attribute__((address_space(3))) unsigned int*)l,
        16, 0, 0);
}

// ---------------------------------------------------------------------------
// C[M,N] = relu(A[M,K] * B[N,K]^T + bias[N]); bf16 in/out, fp32 acc.
// M%128==0, N%BN==0, K%64==0. Wave tile 64 x (BN/2) via 32x32x16 MFMA.
// LDS layout: elem(row,c) at row*64 + (((c>>3) ^ (row&7))*8 + (c&7))
// ---------------------------------------------------------------------------
template<int BN>
__global__ __launch_bounds__(256, 2)
void gemm_bt_bias_relu(const unsigned short* __restrict__ A,
                       const unsigned short* __restrict__ B,
                       const float* __restrict__ bias,
                       unsigned short* __restrict__ C,
                       int M, int N, int K)
{
    constexpr int JT = BN / 32;               // B staging issues
    constexpr int NT = BN / 64;               // B 32-tiles per wave
    __shared__ __align__(16) unsigned short As[128 * BK];   // 16 KB
    __shared__ __align__(16) unsigned short Bs[BN * BK];    // 32/16 KB

    const int tid  = threadIdx.x;
    const int lane = tid & 63;
    const int wave = tid >> 6;
    const int l31  = lane & 31;
    const int kh   = lane >> 5;               // K-half of the 64-lane wave
    const int xa   = lane & 7;                // swizzle factor (row&7)

    const int bm = blockIdx.x * 128;
    const int bn = blockIdx.y * BN;
    const int wm = (wave & 1) * 64;           // wave tile: 64 x (BN/2)
    const int wn = (wave >> 1) * (BN / 2);

    // staging: thread t -> row (t>>3)+32i, swizzled col chunk (t&7)^(row&7).
    const int lrow = tid >> 3;
    const int gcol = ((tid & 7) ^ (lrow & 7)) * 8;

    const unsigned short* gaBase = A + (size_t)(bm + lrow) * K + gcol;
    const unsigned short* gbBase = B + (size_t)(bn + lrow) * K + gcol;

    unsigned short* lA = As + tid * 8;        // uniform base + lane*16B
    unsigned short* lB = Bs + tid * 8;

    const unsigned short* As_w = As + (wm + l31) * BK;
    const unsigned short* Bs_w = Bs + (wn + l31) * BK;

    f32x16 acc[2][NT] = {};

    for (int k0 = 0; k0 < K; k0 += BK) {
#pragma unroll
        for (int i = 0; i < 4; ++i)
            async16(gaBase + (size_t)(i * 32) * K + k0, lA + i * 2048);
#pragma unroll
        for (int i = 0; i < JT; ++i)
            async16(gbBase + (size_t)(i * 32) * K + k0, lB + i * 2048);
        __syncthreads();

#pragma unroll
        for (int s = 0; s < 4; ++s) {         // four K=16 slabs of BK=64
            const int cs = ((2 * s + kh) ^ xa) * 8;
            bf16x8 af[2], bfr[NT];
#pragma unroll
            for (int i = 0; i < 2; ++i)  af[i]  = *(const bf16x8*)(As_w + i * 32 * BK + cs);
#pragma unroll
            for (int j = 0; j < NT; ++j) bfr[j] = *(const bf16x8*)(Bs_w + j * 32 * BK + cs);
#pragma unroll
            for (int i = 0; i < 2; ++i)
#pragma unroll
                for (int j = 0; j < NT; ++j)
                    acc[i][j] = __builtin_amdgcn_mfma_f32_32x32x16_bf16(
                        af[i], bfr[j], acc[i][j], 0, 0, 0);
        }
        __syncthreads();
    }

    float bv[NT];
#pragma unroll
    for (int j = 0; j < NT; ++j) bv[j] = bias[bn + wn + j * 32 + l31];

#pragma unroll
    for (int i = 0; i < 2; ++i) {
        const int rbase = bm + wm + i * 32 + 4 * kh;
#pragma unroll
        for (int j = 0; j < NT; ++j) {
            const int col = bn + wn + j * 32 + l31;
#pragma unroll
            for (int r = 0; r < 16; ++r) {
                const int row = rbase + (r & 3) + 8 * (r >> 2);
                float v = acc[i][j][r] + bv[j];
                v = fmaxf(v, 0.0f);
                C[(size_t)row * N + col] = f2bf(v);
            }
        }
    }
}

// ---------------------------------------------------------------------------
// Merged prep: blocks [0,7680) convert W1..W4 fp32->bf16 (vec4 each thread);
// blocks [7680,11776) cross layer: s=dot(x,cw); h0 = x*s + cb + x (bf16).
// vec4 segments: W1 262144, W2 1048576, W3 524288, W4 131072 (cum 1966080)
// ---------------------------------------------------------------------------
__global__ __launch_bounds__(256)
void prep_kernel(const float* __restrict__ x, const float* __restrict__ cw,
                 const float* __restrict__ cb, unsigned short* __restrict__ h0,
                 const float* __restrict__ s1, const float* __restrict__ s2,
                 const float* __restrict__ s3, const float* __restrict__ s4,
                 unsigned short* __restrict__ d1, unsigned short* __restrict__ d2,
                 unsigned short* __restrict__ d3, unsigned short* __restrict__ d4)
{
    const int b = blockIdx.x;
    if (b < 7680) {
        long t = (long)b * 256 + threadIdx.x;
        const float* s; unsigned short* d; long off;
        if (t < 262144L)       { s = s1; d = d1; off = t; }
        else if (t < 1310720L) { s = s2; d = d2; off = t - 262144L; }
        else if (t < 1835008L) { s = s3; d = d3; off = t - 1310720L; }
        else                   { s = s4; d = d4; off = t - 1835008L; }
        f32x4 f = *(const f32x4*)(s + off * 4);
        u16x4 o;
#pragma unroll
        for (int i = 0; i < 4; ++i) o[i] = f2bf(f[i]);
        *(u16x4*)(d + off * 4) = o;
    } else {
        const int row  = (b - 7680) * 4 + (threadIdx.x >> 6);
        const int lane = threadIdx.x & 63;
        const float* xr = x + (size_t)row * 512;
        float xv[8];
        float s = 0.f;
#pragma unroll
        for (int i = 0; i < 8; ++i) {
            const int c = lane + i * 64;
            xv[i] = xr[c];
            s += xv[i] * cw[c];
        }
#pragma unroll
        for (int off = 32; off > 0; off >>= 1) s += __shfl_down(s, off, 64);
        s = __shfl(s, 0, 64);
        unsigned short* hr = h0 + (size_t)row * 512;
#pragma unroll
        for (int i = 0; i < 8; ++i) {
            const int c = lane + i * 64;
            hr[c] = f2bf(xv[i] * s + cb[c] + xv[i]);
        }
    }
}

// ---------------------------------------------------------------------------
// Final head: out[m] = dot(h4[m,:512], Wo) + bo   (fp32)
// ---------------------------------------------------------------------------
__global__ __launch_bounds__(256)
void final_dot(const unsigned short* __restrict__ h4, const float* __restrict__ Wo,
               const float* __restrict__ bo, float* __restrict__ out)
{
    const int row  = blockIdx.x * 4 + (threadIdx.x >> 6);
    const int lane = threadIdx.x & 63;
    const unsigned short* hr = h4 + (size_t)row * 512;
    float s = 0.f;
#pragma unroll
    for (int i = 0; i < 8; ++i) {
        const int c = lane + i * 64;
        s += bf2f(hr[c]) * Wo[c];
    }
#pragma unroll
    for (int off = 32; off > 0; off >>= 1) s += __shfl_down(s, off, 64);
    if (lane == 0) out[row] = s + bo[0];
}

// ---------------------------------------------------------------------------
extern "C" void kernel_launch(void* const* d_in, const int* in_sizes, int n_in,
                              void* d_out, int out_size, void* d_ws, size_t ws_size,
                              hipStream_t stream)
{
    const float* x  = (const float*)d_in[0];
    const float* cw = (const float*)d_in[1];
    const float* cb = (const float*)d_in[2];
    const float* W1 = (const float*)d_in[3];  const float* b1 = (const float*)d_in[4];
    const float* W2 = (const float*)d_in[5];  const float* b2 = (const float*)d_in[6];
    const float* W3 = (const float*)d_in[7];  const float* b3 = (const float*)d_in[8];
    const float* W4 = (const float*)d_in[9];  const float* b4 = (const float*)d_in[10];
    const float* Wo = (const float*)d_in[11]; const float* bo = (const float*)d_in[12];
    float* out = (float*)d_out;

    // workspace carve (~143 MB)
    char* p = (char*)d_ws;
    unsigned short* wb1 = (unsigned short*)p; p += (size_t)2048 * 512  * 2;
    unsigned short* wb2 = (unsigned short*)p; p += (size_t)2048 * 2048 * 2;
    unsigned short* wb3 = (unsigned short*)p; p += (size_t)1024 * 2048 * 2;
    unsigned short* wb4 = (unsigned short*)p; p += (size_t)512  * 1024 * 2;
    unsigned short* actA = (unsigned short*)p; p += (size_t)16384 * 2048 * 2; // h0,h2,h4
    unsigned short* actB = (unsigned short*)p;                                // h1,h3

    prep_kernel<<<11776, 256, 0, stream>>>(x, cw, cb, actA,
                                           W1, W2, W3, W4, wb1, wb2, wb3, wb4);

    // h1 = relu(h0 @ W1^T + b1)   [16384,2048], K=512
    gemm_bt_bias_relu<256><<<dim3(128, 8), 256, 0, stream>>>(actA, wb1, b1, actB, 16384, 2048, 512);
    // h2 = relu(h1 @ W2^T + b2)   [16384,2048], K=2048
    gemm_bt_bias_relu<256><<<dim3(128, 8), 256, 0, stream>>>(actB, wb2, b2, actA, 16384, 2048, 2048);
    // h3 = relu(h2 @ W3^T + b3)   [16384,1024], K=2048
    gemm_bt_bias_relu<256><<<dim3(128, 4), 256, 0, stream>>>(actA, wb3, b3, actB, 16384, 1024, 2048);
    // h4 = relu(h3 @ W4^T + b4)   [16384,512], K=1024  (BN=128 -> 512 blocks)
    gemm_bt_bias_relu<128><<<dim3(128, 4), 256, 0, stream>>>(actB, wb4, b4, actA, 16384, 512, 1024);
    // out = h4 @ Wo^T + bo        [16384,1]
    final_dot<<<4096, 256, 0, stream>>>(actA, Wo, bo, out);
}

// Round 6
// 368.966 us; speedup vs baseline: 1.0379x; 1.0379x over previous
//
#include <hip/hip_runtime.h>

// Simple_Cross2: x[16384,512] -> cross -> 2048 -> 2048 -> 1024 -> 512 -> 1
// bf16 MFMA (16x16x32) GEMMs, fp32 accumulate, fused bias+relu.
// R2: BK=64 + XOR swizzle -> 0 bank conflicts.
// R3: 64x128 wave tile, block 128x256 -> MfmaUtil 50%, G2 119us. BEST GEMM.
// R4 FAILED: dbuf prefetch (barrier drains vmcnt(0) incl. prefetch).
// R5 FAILED: 32x32x16 shape (conflicts back: 1.26e7 -- lane>>5 chunk keying
//     aliases in LDS phases; 16x16 lane>>4 keying is the proven-free pattern).
// R6: consolidate on R3 GEMM + attack non-G2 time (~237us flat since R1):
//     G4 BN=128 (2 blk/CU not 1), head fused into G4 epilogue (atomicAdd,
//     h4 never materialized, final_dot gone), bn-fast grid order for L2
//     A-tile sharing, out pre-init to bo in prep.

#define BK 64

typedef __bf16 bf16x8 __attribute__((ext_vector_type(8)));
typedef float  f32x4  __attribute__((ext_vector_type(4)));
typedef unsigned short u16x4 __attribute__((ext_vector_type(4)));

__device__ __forceinline__ unsigned short f2bf(float f) {
    unsigned int u = __builtin_bit_cast(unsigned int, f);
    u += 0x7fffu + ((u >> 16) & 1u);          // round-to-nearest-even
    return (unsigned short)(u >> 16);
}

__device__ __forceinline__ void async16(const void* g, void* l) {
    __builtin_amdgcn_global_load_lds(
        (const __attribute__((address_space(1))) unsigned int*)g,
        (__attribute__((address_space(3))) unsigned int*)l,
        16, 0, 0);
}

// ---------------------------------------------------------------------------
// C[M,N] = relu(A[M,K] * B[N,K]^T + bias[N]); bf16 in/out, fp32 acc.
// Exact R3 inner loop. bn = blockIdx.x (fast) for L2 A-tile sharing.
// LDS layout: elem(row,c) at row*64 + (((c>>3) ^ (row&7))*8 + (c&7))
// ---------------------------------------------------------------------------
template<int BN>
__global__ __launch_bounds__(256, 2)
void gemm_bt_bias_relu(const unsigned short* __restrict__ A,
                       const unsigned short* __restrict__ B,
                       const float* __restrict__ bias,
                       unsigned short* __restrict__ C,
                       int M, int N, int K)
{
    constexpr int JT = BN / 32;               // staging issues / acc cols
    __shared__ __align__(16) unsigned short As[128 * BK];
    __shared__ __align__(16) unsigned short Bs[BN * BK];

    const int tid  = threadIdx.x;
    const int lane = tid & 63;
    const int wave = tid >> 6;
    const int quad = lane >> 4;
    const int l16  = lane & 15;

    const int bm = blockIdx.y * 128;
    const int bn = blockIdx.x * BN;
    const int wm = (wave & 1) * 64;           // wave tile: 64 x (BN/2)
    const int wn = (wave >> 1) * (BN / 2);

    const int lrow = tid >> 3;
    const int gcol = ((tid & 7) ^ (lrow & 7)) * 8;

    const unsigned short* gaBase = A + (size_t)(bm + lrow) * K + gcol;
    const unsigned short* gbBase = B + (size_t)(bn + lrow) * K + gcol;

    unsigned short* lA = As + tid * 8;
    unsigned short* lB = Bs + tid * 8;

    const int xa = l16 & 7;
    const unsigned short* As_w = As + (wm + l16) * BK;
    const unsigned short* Bs_w = Bs + (wn + l16) * BK;
    const int c0 = (quad ^ xa) * 8;
    const int c1 = ((quad ^ 4) ^ xa) * 8;

    f32x4 acc[4][JT] = {};

    for (int k0 = 0; k0 < K; k0 += BK) {
#pragma unroll
        for (int i = 0; i < 4; ++i)
            async16(gaBase + (size_t)(i * 32) * K + k0, lA + i * 2048);
#pragma unroll
        for (int i = 0; i < JT; ++i)
            async16(gbBase + (size_t)(i * 32) * K + k0, lB + i * 2048);
        __syncthreads();

#pragma unroll
        for (int kk = 0; kk < 2; ++kk) {
            const int cs = kk ? c1 : c0;
            bf16x8 af[4], bfr[JT];
#pragma unroll
            for (int i = 0; i < 4; ++i)  af[i]  = *(const bf16x8*)(As_w + i * 16 * BK + cs);
#pragma unroll
            for (int j = 0; j < JT; ++j) bfr[j] = *(const bf16x8*)(Bs_w + j * 16 * BK + cs);
#pragma unroll
            for (int i = 0; i < 4; ++i)
#pragma unroll
                for (int j = 0; j < JT; ++j)
                    acc[i][j] = __builtin_amdgcn_mfma_f32_16x16x32_bf16(
                        af[i], bfr[j], acc[i][j], 0, 0, 0);
        }
        __syncthreads();
    }

    float bv[JT];
#pragma unroll
    for (int j = 0; j < JT; ++j) bv[j] = bias[bn + wn + j * 16 + l16];

#pragma unroll
    for (int i = 0; i < 4; ++i) {
        const int row0 = bm + wm + i * 16 + quad * 4;
#pragma unroll
        for (int j = 0; j < JT; ++j) {
            const int col = bn + wn + j * 16 + l16;
#pragma unroll
            for (int r = 0; r < 4; ++r) {
                float v = acc[i][j][r] + bv[j];
                v = fmaxf(v, 0.0f);
                C[(size_t)(row0 + r) * N + col] = f2bf(v);
            }
        }
    }
}

// ---------------------------------------------------------------------------
// G4 + head fused: h4 = relu(A @ W4^T + b4) is NOT stored; instead each block
// computes partial dot(h4_row, Wo_cols) and atomicAdds into out[row].
// out must be pre-initialized to bo (done in prep_kernel).
// BN=128 fixed: block tile 128x128, wave tile 64x64, acc[4][4].
// ---------------------------------------------------------------------------
__global__ __launch_bounds__(256, 2)
void gemm_bt_head(const unsigned short* __restrict__ A,
                  const unsigned short* __restrict__ B,
                  const float* __restrict__ bias,
                  const float* __restrict__ Wo,
                  float* __restrict__ out,
                  int M, int N, int K)
{
    constexpr int BN = 128;
    constexpr int JT = 4;
    __shared__ __align__(16) unsigned short As[128 * BK];
    __shared__ __align__(16) unsigned short Bs[BN * BK];

    const int tid  = threadIdx.x;
    const int lane = tid & 63;
    const int wave = tid >> 6;
    const int quad = lane >> 4;
    const int l16  = lane & 15;

    const int bm = blockIdx.y * 128;
    const int bn = blockIdx.x * BN;
    const int wm = (wave & 1) * 64;
    const int wn = (wave >> 1) * 64;

    const int lrow = tid >> 3;
    const int gcol = ((tid & 7) ^ (lrow & 7)) * 8;

    const unsigned short* gaBase = A + (size_t)(bm + lrow) * K + gcol;
    const unsigned short* gbBase = B + (size_t)(bn + lrow) * K + gcol;

    unsigned short* lA = As + tid * 8;
    unsigned short* lB = Bs + tid * 8;

    const int xa = l16 & 7;
    const unsigned short* As_w = As + (wm + l16) * BK;
    const unsigned short* Bs_w = Bs + (wn + l16) * BK;
    const int c0 = (quad ^ xa) * 8;
    const int c1 = ((quad ^ 4) ^ xa) * 8;

    f32x4 acc[4][JT] = {};

    for (int k0 = 0; k0 < K; k0 += BK) {
#pragma unroll
        for (int i = 0; i < 4; ++i)
            async16(gaBase + (size_t)(i * 32) * K + k0, lA + i * 2048);
#pragma unroll
        for (int i = 0; i < JT; ++i)
            async16(gbBase + (size_t)(i * 32) * K + k0, lB + i * 2048);
        __syncthreads();

#pragma unroll
        for (int kk = 0; kk < 2; ++kk) {
            const int cs = kk ? c1 : c0;
            bf16x8 af[4], bfr[JT];
#pragma unroll
            for (int i = 0; i < 4; ++i)  af[i]  = *(const bf16x8*)(As_w + i * 16 * BK + cs);
#pragma unroll
            for (int j = 0; j < JT; ++j) bfr[j] = *(const bf16x8*)(Bs_w + j * 16 * BK + cs);
#pragma unroll
            for (int i = 0; i < 4; ++i)
#pragma unroll
                for (int j = 0; j < JT; ++j)
                    acc[i][j] = __builtin_amdgcn_mfma_f32_16x16x32_bf16(
                        af[i], bfr[j], acc[i][j], 0, 0, 0);
        }
        __syncthreads();
    }

    float bv[JT], wov[JT];
#pragma unroll
    for (int j = 0; j < JT; ++j) {
        const int col = bn + wn + j * 16 + l16;
        bv[j]  = bias[col];
        wov[j] = Wo[col];
    }

    // per-lane partial dot over this lane's 4 columns, relu applied; then
    // reduce over l16 (bits 0-3 of lane; quad bits 4-5 untouched by xor<16)
#pragma unroll
    for (int i = 0; i < 4; ++i) {
#pragma unroll
        for (int r = 0; r < 4; ++r) {
            float ws = 0.f;
#pragma unroll
            for (int j = 0; j < JT; ++j) {
                float v = acc[i][j][r] + bv[j];
                v = fmaxf(v, 0.0f);            // h4 value (fp32, pre-bf16-round)
                ws += v * wov[j];
            }
#pragma unroll
            for (int off = 8; off > 0; off >>= 1)
                ws += __shfl_xor(ws, off, 64);
            if (l16 == 0) {
                const int row = bm + wm + i * 16 + quad * 4 + r;
                atomicAdd(&out[row], ws);
            }
        }
    }
}

// ---------------------------------------------------------------------------
// Merged prep: [0,7680) convert W1..W4 fp32->bf16; [7680,11776) cross layer;
// [11776,11840) init out[m] = bo.
// vec4 segments: W1 262144, W2 1048576, W3 524288, W4 131072 (cum 1966080)
// ---------------------------------------------------------------------------
__global__ __launch_bounds__(256)
void prep_kernel(const float* __restrict__ x, const float* __restrict__ cw,
                 const float* __restrict__ cb, unsigned short* __restrict__ h0,
                 const float* __restrict__ s1, const float* __restrict__ s2,
                 const float* __restrict__ s3, const float* __restrict__ s4,
                 unsigned short* __restrict__ d1, unsigned short* __restrict__ d2,
                 unsigned short* __restrict__ d3, unsigned short* __restrict__ d4,
                 const float* __restrict__ bo, float* __restrict__ out)
{
    const int b = blockIdx.x;
    if (b < 7680) {
        long t = (long)b * 256 + threadIdx.x;
        const float* s; unsigned short* d; long off;
        if (t < 262144L)       { s = s1; d = d1; off = t; }
        else if (t < 1310720L) { s = s2; d = d2; off = t - 262144L; }
        else if (t < 1835008L) { s = s3; d = d3; off = t - 1310720L; }
        else                   { s = s4; d = d4; off = t - 1835008L; }
        f32x4 f = *(const f32x4*)(s + off * 4);
        u16x4 o;
#pragma unroll
        for (int i = 0; i < 4; ++i) o[i] = f2bf(f[i]);
        *(u16x4*)(d + off * 4) = o;
    } else if (b < 11776) {
        const int row  = (b - 7680) * 4 + (threadIdx.x >> 6);
        const int lane = threadIdx.x & 63;
        const float* xr = x + (size_t)row * 512;
        float xv[8];
        float s = 0.f;
#pragma unroll
        for (int i = 0; i < 8; ++i) {
            const int c = lane + i * 64;
            xv[i] = xr[c];
            s += xv[i] * cw[c];
        }
#pragma unroll
        for (int off = 32; off > 0; off >>= 1) s += __shfl_down(s, off, 64);
        s = __shfl(s, 0, 64);
        unsigned short* hr = h0 + (size_t)row * 512;
#pragma unroll
        for (int i = 0; i < 8; ++i) {
            const int c = lane + i * 64;
            hr[c] = f2bf(xv[i] * s + cb[c] + xv[i]);
        }
    } else {
        const int t = (b - 11776) * 256 + threadIdx.x;   // 64 blocks = 16384
        out[t] = bo[0];
    }
}

// ---------------------------------------------------------------------------
extern "C" void kernel_launch(void* const* d_in, const int* in_sizes, int n_in,
                              void* d_out, int out_size, void* d_ws, size_t ws_size,
                              hipStream_t stream)
{
    const float* x  = (const float*)d_in[0];
    const float* cw = (const float*)d_in[1];
    const float* cb = (const float*)d_in[2];
    const float* W1 = (const float*)d_in[3];  const float* b1 = (const float*)d_in[4];
    const float* W2 = (const float*)d_in[5];  const float* b2 = (const float*)d_in[6];
    const float* W3 = (const float*)d_in[7];  const float* b3 = (const float*)d_in[8];
    const float* W4 = (const float*)d_in[9];  const float* b4 = (const float*)d_in[10];
    const float* Wo = (const float*)d_in[11]; const float* bo = (const float*)d_in[12];
    float* out = (float*)d_out;

    // workspace carve (~143 MB)
    char* p = (char*)d_ws;
    unsigned short* wb1 = (unsigned short*)p; p += (size_t)2048 * 512  * 2;
    unsigned short* wb2 = (unsigned short*)p; p += (size_t)2048 * 2048 * 2;
    unsigned short* wb3 = (unsigned short*)p; p += (size_t)1024 * 2048 * 2;
    unsigned short* wb4 = (unsigned short*)p; p += (size_t)512  * 1024 * 2;
    unsigned short* actA = (unsigned short*)p; p += (size_t)16384 * 2048 * 2; // h0,h2
    unsigned short* actB = (unsigned short*)p;                                // h1,h3

    prep_kernel<<<11840, 256, 0, stream>>>(x, cw, cb, actA,
                                           W1, W2, W3, W4, wb1, wb2, wb3, wb4,
                                           bo, out);

    // h1 = relu(h0 @ W1^T + b1)   [16384,2048], K=512
    gemm_bt_bias_relu<256><<<dim3(8, 128), 256, 0, stream>>>(actA, wb1, b1, actB, 16384, 2048, 512);
    // h2 = relu(h1 @ W2^T + b2)   [16384,2048], K=2048
    gemm_bt_bias_relu<256><<<dim3(8, 128), 256, 0, stream>>>(actB, wb2, b2, actA, 16384, 2048, 2048);
    // h3 = relu(h2 @ W3^T + b3)   [16384,1024], K=2048
    gemm_bt_bias_relu<256><<<dim3(4, 128), 256, 0, stream>>>(actA, wb3, b3, actB, 16384, 1024, 2048);
    // out += sum_cols relu(h3 @ W4^T + b4) * Wo   [16384,512] fused head
    gemm_bt_head<<<dim3(4, 128), 256, 0, stream>>>(actB, wb4, b4, Wo, out, 16384, 512, 1024);
}

// Round 7
// 345.494 us; speedup vs baseline: 1.1084x; 1.0679x over previous
//
#include <hip/hip_runtime.h>

// Simple_Cross2: x[16384,512] -> cross -> 2048 -> 2048 -> 1024 -> 512 -> 1
// bf16 MFMA (16x16x32) GEMMs, fp32 accumulate, fused bias+relu.
// R2: BK=64 + XOR swizzle -> 0 bank conflicts.
// R3: 64x128 wave tile, block 128x256, bm-fast grid -> G2 119us. BEST GEMM.
// R4 FAILED: dbuf prefetch (barrier drains vmcnt(0) incl. prefetch).
// R5 FAILED: 32x32x16 shape (conflicts back; 16x16 lane>>4 keying is proven).
// R6 MIXED: head fusion + G4 BN=128 good (~-13us); bn-fast grid BAD
//     (FETCH 100->270MB: A no longer L3-resident across bn-groups; G2 +21us).
// R7: revert grid to bm-fast (A stays L3-resident), keep fusion/prep/G4=128.

#define BK 64

typedef __bf16 bf16x8 __attribute__((ext_vector_type(8)));
typedef float  f32x4  __attribute__((ext_vector_type(4)));
typedef unsigned short u16x4 __attribute__((ext_vector_type(4)));

__device__ __forceinline__ unsigned short f2bf(float f) {
    unsigned int u = __builtin_bit_cast(unsigned int, f);
    u += 0x7fffu + ((u >> 16) & 1u);          // round-to-nearest-even
    return (unsigned short)(u >> 16);
}

__device__ __forceinline__ void async16(const void* g, void* l) {
    __builtin_amdgcn_global_load_lds(
        (const __attribute__((address_space(1))) unsigned int*)g,
        (__attribute__((address_space(3))) unsigned int*)l,
        16, 0, 0);
}

// ---------------------------------------------------------------------------
// C[M,N] = relu(A[M,K] * B[N,K]^T + bias[N]); bf16 in/out, fp32 acc.
// Exact R3 inner loop; bm = blockIdx.x (fast) keeps A L3-resident per bn-group.
// LDS layout: elem(row,c) at row*64 + (((c>>3) ^ (row&7))*8 + (c&7))
// ---------------------------------------------------------------------------
template<int BN>
__global__ __launch_bounds__(256, 2)
void gemm_bt_bias_relu(const unsigned short* __restrict__ A,
                       const unsigned short* __restrict__ B,
                       const float* __restrict__ bias,
                       unsigned short* __restrict__ C,
                       int M, int N, int K)
{
    constexpr int JT = BN / 32;               // staging issues / acc cols
    __shared__ __align__(16) unsigned short As[128 * BK];
    __shared__ __align__(16) unsigned short Bs[BN * BK];

    const int tid  = threadIdx.x;
    const int lane = tid & 63;
    const int wave = tid >> 6;
    const int quad = lane >> 4;
    const int l16  = lane & 15;

    const int bm = blockIdx.x * 128;
    const int bn = blockIdx.y * BN;
    const int wm = (wave & 1) * 64;           // wave tile: 64 x (BN/2)
    const int wn = (wave >> 1) * (BN / 2);

    const int lrow = tid >> 3;
    const int gcol = ((tid & 7) ^ (lrow & 7)) * 8;

    const unsigned short* gaBase = A + (size_t)(bm + lrow) * K + gcol;
    const unsigned short* gbBase = B + (size_t)(bn + lrow) * K + gcol;

    unsigned short* lA = As + tid * 8;
    unsigned short* lB = Bs + tid * 8;

    const int xa = l16 & 7;
    const unsigned short* As_w = As + (wm + l16) * BK;
    const unsigned short* Bs_w = Bs + (wn + l16) * BK;
    const int c0 = (quad ^ xa) * 8;
    const int c1 = ((quad ^ 4) ^ xa) * 8;

    f32x4 acc[4][JT] = {};

    for (int k0 = 0; k0 < K; k0 += BK) {
#pragma unroll
        for (int i = 0; i < 4; ++i)
            async16(gaBase + (size_t)(i * 32) * K + k0, lA + i * 2048);
#pragma unroll
        for (int i = 0; i < JT; ++i)
            async16(gbBase + (size_t)(i * 32) * K + k0, lB + i * 2048);
        __syncthreads();

#pragma unroll
        for (int kk = 0; kk < 2; ++kk) {
            const int cs = kk ? c1 : c0;
            bf16x8 af[4], bfr[JT];
#pragma unroll
            for (int i = 0; i < 4; ++i)  af[i]  = *(const bf16x8*)(As_w + i * 16 * BK + cs);
#pragma unroll
            for (int j = 0; j < JT; ++j) bfr[j] = *(const bf16x8*)(Bs_w + j * 16 * BK + cs);
#pragma unroll
            for (int i = 0; i < 4; ++i)
#pragma unroll
                for (int j = 0; j < JT; ++j)
                    acc[i][j] = __builtin_amdgcn_mfma_f32_16x16x32_bf16(
                        af[i], bfr[j], acc[i][j], 0, 0, 0);
        }
        __syncthreads();
    }

    float bv[JT];
#pragma unroll
    for (int j = 0; j < JT; ++j) bv[j] = bias[bn + wn + j * 16 + l16];

#pragma unroll
    for (int i = 0; i < 4; ++i) {
        const int row0 = bm + wm + i * 16 + quad * 4;
#pragma unroll
        for (int j = 0; j < JT; ++j) {
            const int col = bn + wn + j * 16 + l16;
#pragma unroll
            for (int r = 0; r < 4; ++r) {
                float v = acc[i][j][r] + bv[j];
                v = fmaxf(v, 0.0f);
                C[(size_t)(row0 + r) * N + col] = f2bf(v);
            }
        }
    }
}

// ---------------------------------------------------------------------------
// G4 + head fused: h4 = relu(A @ W4^T + b4) is NOT stored; each block
// computes partial dot(h4_row, Wo_cols) and atomicAdds into out[row].
// out pre-initialized to bo in prep_kernel. Block tile 128x128, acc[4][4].
// ---------------------------------------------------------------------------
__global__ __launch_bounds__(256, 2)
void gemm_bt_head(const unsigned short* __restrict__ A,
                  const unsigned short* __restrict__ B,
                  const float* __restrict__ bias,
                  const float* __restrict__ Wo,
                  float* __restrict__ out,
                  int M, int N, int K)
{
    constexpr int BN = 128;
    constexpr int JT = 4;
    __shared__ __align__(16) unsigned short As[128 * BK];
    __shared__ __align__(16) unsigned short Bs[BN * BK];

    const int tid  = threadIdx.x;
    const int lane = tid & 63;
    const int wave = tid >> 6;
    const int quad = lane >> 4;
    const int l16  = lane & 15;

    const int bm = blockIdx.x * 128;
    const int bn = blockIdx.y * BN;
    const int wm = (wave & 1) * 64;
    const int wn = (wave >> 1) * 64;

    const int lrow = tid >> 3;
    const int gcol = ((tid & 7) ^ (lrow & 7)) * 8;

    const unsigned short* gaBase = A + (size_t)(bm + lrow) * K + gcol;
    const unsigned short* gbBase = B + (size_t)(bn + lrow) * K + gcol;

    unsigned short* lA = As + tid * 8;
    unsigned short* lB = Bs + tid * 8;

    const int xa = l16 & 7;
    const unsigned short* As_w = As + (wm + l16) * BK;
    const unsigned short* Bs_w = Bs + (wn + l16) * BK;
    const int c0 = (quad ^ xa) * 8;
    const int c1 = ((quad ^ 4) ^ xa) * 8;

    f32x4 acc[4][JT] = {};

    for (int k0 = 0; k0 < K; k0 += BK) {
#pragma unroll
        for (int i = 0; i < 4; ++i)
            async16(gaBase + (size_t)(i * 32) * K + k0, lA + i * 2048);
#pragma unroll
        for (int i = 0; i < JT; ++i)
            async16(gbBase + (size_t)(i * 32) * K + k0, lB + i * 2048);
        __syncthreads();

#pragma unroll
        for (int kk = 0; kk < 2; ++kk) {
            const int cs = kk ? c1 : c0;
            bf16x8 af[4], bfr[JT];
#pragma unroll
            for (int i = 0; i < 4; ++i)  af[i]  = *(const bf16x8*)(As_w + i * 16 * BK + cs);
#pragma unroll
            for (int j = 0; j < JT; ++j) bfr[j] = *(const bf16x8*)(Bs_w + j * 16 * BK + cs);
#pragma unroll
            for (int i = 0; i < 4; ++i)
#pragma unroll
                for (int j = 0; j < JT; ++j)
                    acc[i][j] = __builtin_amdgcn_mfma_f32_16x16x32_bf16(
                        af[i], bfr[j], acc[i][j], 0, 0, 0);
        }
        __syncthreads();
    }

    float bv[JT], wov[JT];
#pragma unroll
    for (int j = 0; j < JT; ++j) {
        const int col = bn + wn + j * 16 + l16;
        bv[j]  = bias[col];
        wov[j] = Wo[col];
    }

#pragma unroll
    for (int i = 0; i < 4; ++i) {
#pragma unroll
        for (int r = 0; r < 4; ++r) {
            float ws = 0.f;
#pragma unroll
            for (int j = 0; j < JT; ++j) {
                float v = acc[i][j][r] + bv[j];
                v = fmaxf(v, 0.0f);
                ws += v * wov[j];
            }
#pragma unroll
            for (int off = 8; off > 0; off >>= 1)
                ws += __shfl_xor(ws, off, 64);
            if (l16 == 0) {
                const int row = bm + wm + i * 16 + quad * 4 + r;
                atomicAdd(&out[row], ws);
            }
        }
    }
}

// ---------------------------------------------------------------------------
// Merged prep: [0,7680) convert W1..W4 fp32->bf16; [7680,11776) cross layer;
// [11776,11840) init out[m] = bo.
// vec4 segments: W1 262144, W2 1048576, W3 524288, W4 131072 (cum 1966080)
// ---------------------------------------------------------------------------
__global__ __launch_bounds__(256)
void prep_kernel(const float* __restrict__ x, const float* __restrict__ cw,
                 const float* __restrict__ cb, unsigned short* __restrict__ h0,
                 const float* __restrict__ s1, const float* __restrict__ s2,
                 const float* __restrict__ s3, const float* __restrict__ s4,
                 unsigned short* __restrict__ d1, unsigned short* __restrict__ d2,
                 unsigned short* __restrict__ d3, unsigned short* __restrict__ d4,
                 const float* __restrict__ bo, float* __restrict__ out)
{
    const int b = blockIdx.x;
    if (b < 7680) {
        long t = (long)b * 256 + threadIdx.x;
        const float* s; unsigned short* d; long off;
        if (t < 262144L)       { s = s1; d = d1; off = t; }
        else if (t < 1310720L) { s = s2; d = d2; off = t - 262144L; }
        else if (t < 1835008L) { s = s3; d = d3; off = t - 1310720L; }
        else                   { s = s4; d = d4; off = t - 1835008L; }
        f32x4 f = *(const f32x4*)(s + off * 4);
        u16x4 o;
#pragma unroll
        for (int i = 0; i < 4; ++i) o[i] = f2bf(f[i]);
        *(u16x4*)(d + off * 4) = o;
    } else if (b < 11776) {
        const int row  = (b - 7680) * 4 + (threadIdx.x >> 6);
        const int lane = threadIdx.x & 63;
        const float* xr = x + (size_t)row * 512;
        float xv[8];
        float s = 0.f;
#pragma unroll
        for (int i = 0; i < 8; ++i) {
            const int c = lane + i * 64;
            xv[i] = xr[c];
            s += xv[i] * cw[c];
        }
#pragma unroll
        for (int off = 32; off > 0; off >>= 1) s += __shfl_down(s, off, 64);
        s = __shfl(s, 0, 64);
        unsigned short* hr = h0 + (size_t)row * 512;
#pragma unroll
        for (int i = 0; i < 8; ++i) {
            const int c = lane + i * 64;
            hr[c] = f2bf(xv[i] * s + cb[c] + xv[i]);
        }
    } else {
        const int t = (b - 11776) * 256 + threadIdx.x;   // 64 blocks = 16384
        out[t] = bo[0];
    }
}

// ---------------------------------------------------------------------------
extern "C" void kernel_launch(void* const* d_in, const int* in_sizes, int n_in,
                              void* d_out, int out_size, void* d_ws, size_t ws_size,
                              hipStream_t stream)
{
    const float* x  = (const float*)d_in[0];
    const float* cw = (const float*)d_in[1];
    const float* cb = (const float*)d_in[2];
    const float* W1 = (const float*)d_in[3];  const float* b1 = (const float*)d_in[4];
    const float* W2 = (const float*)d_in[5];  const float* b2 = (const float*)d_in[6];
    const float* W3 = (const float*)d_in[7];  const float* b3 = (const float*)d_in[8];
    const float* W4 = (const float*)d_in[9];  const float* b4 = (const float*)d_in[10];
    const float* Wo = (const float*)d_in[11]; const float* bo = (const float*)d_in[12];
    float* out = (float*)d_out;

    // workspace carve (~143 MB)
    char* p = (char*)d_ws;
    unsigned short* wb1 = (unsigned short*)p; p += (size_t)2048 * 512  * 2;
    unsigned short* wb2 = (unsigned short*)p; p += (size_t)2048 * 2048 * 2;
    unsigned short* wb3 = (unsigned short*)p; p += (size_t)1024 * 2048 * 2;
    unsigned short* wb4 = (unsigned short*)p; p += (size_t)512  * 1024 * 2;
    unsigned short* actA = (unsigned short*)p; p += (size_t)16384 * 2048 * 2; // h0,h2
    unsigned short* actB = (unsigned short*)p;                                // h1,h3

    prep_kernel<<<11840, 256, 0, stream>>>(x, cw, cb, actA,
                                           W1, W2, W3, W4, wb1, wb2, wb3, wb4,
                                           bo, out);

    // h1 = relu(h0 @ W1^T + b1)   [16384,2048], K=512
    gemm_bt_bias_relu<256><<<dim3(128, 8), 256, 0, stream>>>(actA, wb1, b1, actB, 16384, 2048, 512);
    // h2 = relu(h1 @ W2^T + b2)   [16384,2048], K=2048
    gemm_bt_bias_relu<256><<<dim3(128, 8), 256, 0, stream>>>(actB, wb2, b2, actA, 16384, 2048, 2048);
    // h3 = relu(h2 @ W3^T + b3)   [16384,1024], K=2048
    gemm_bt_bias_relu<256><<<dim3(128, 4), 256, 0, stream>>>(actA, wb3, b3, actB, 16384, 1024, 2048);
    // out += sum_cols relu(h3 @ W4^T + b4) * Wo   [16384,512] fused head
    gemm_bt_head<<<dim3(128, 4), 256, 0, stream>>>(actB, wb4, b4, Wo, out, 16384, 512, 1024);
}